// Round 1
// baseline (355.065 us; speedup 1.0000x reference)
//
#include <hip/hip_runtime.h>
#include <hip/hip_fp16.h>

typedef _Float16 half8 __attribute__((ext_vector_type(8)));
typedef float f32x4 __attribute__((ext_vector_type(4)));

#define BB 32
#define NN 2048
#define DD 256
#define SCALE 0.0625f

// ---- P1: Wt[mat][c][k] = W[k][c], f16.  (mat 0 = Wq, 1 = Wk)
__global__ void k_cvt_w(const float* __restrict__ Wq, const float* __restrict__ Wk,
                        _Float16* __restrict__ Wt) {
    int idx = blockIdx.x * 256 + threadIdx.x;  // 131072 total
    int mat = idx >> 16;
    int c = (idx >> 8) & 255;
    int k = idx & 255;
    const float* W = mat ? Wk : Wq;
    Wt[idx] = (_Float16)W[k * 256 + c];
}

// ---- P2: wv[d] = sum_e Wv[d,e]*Ww[e]; wv[256] = bv.Ww + bw
__global__ void k_wv(const float* __restrict__ Wv, const float* __restrict__ bv,
                     const float* __restrict__ Ww, const float* __restrict__ bw,
                     float* __restrict__ wv) {
    int d = threadIdx.x;
    float acc = 0.f;
    for (int e = 0; e < DD; ++e) acc += Wv[d * DD + e] * Ww[e];
    wv[d] = acc;
    if (d == 0) {
        float c = 0.f;
        for (int e = 0; e < DD; ++e) c += bv[e] * Ww[e];
        wv[DD] = c + bw[0];
    }
}

// ---- P3: S[r] = x[r,:].wv + wv[256]   (one wave per row-iteration)
__global__ void k_s(const float* __restrict__ x, const float* __restrict__ wv,
                    float* __restrict__ S) {
    int gtid = blockIdx.x * 256 + threadIdx.x;
    int wave = gtid >> 6;
    int lane = threadIdx.x & 63;
    f32x4 wvv = *((const f32x4*)wv + lane);
    float cst = wv[DD];
    for (int r = wave; r < BB * NN; r += 1024) {
        f32x4 xv = *((const f32x4*)(x + (long)r * DD) + lane);
        float p = xv[0] * wvv[0] + xv[1] * wvv[1] + xv[2] * wvv[2] + xv[3] * wvv[3];
        #pragma unroll
        for (int m = 1; m < 64; m <<= 1) p += __shfl_xor(p, m, 64);
        if (lane == 0) S[r] = p + cst;
    }
}

// ---- K1: Q/K projection GEMM.  grid (512 row-tiles, 2 mats), 512 threads.
// Block computes 128 rows x 256 cols of (x @ W + b), stores f16.
__global__ __launch_bounds__(512) void k_proj(
    const float* __restrict__ x, const _Float16* __restrict__ Wt,
    const float* __restrict__ bq, const float* __restrict__ bk,
    _Float16* __restrict__ Qh, _Float16* __restrict__ Kh) {
    __shared__ _Float16 As[128][40];  // 32 k-cols + 8 pad (16B-aligned rows, ~2-way banks)
    int mat = blockIdx.y;
    int m0 = blockIdx.x * 128;
    const _Float16* Wm = Wt + mat * 65536;
    const float* bias = mat ? bk : bq;
    _Float16* Out = mat ? Kh : Qh;
    int tid = threadIdx.x, w = tid >> 6, l = tid & 63;
    int wr = w >> 2, wc = w & 3;       // wave -> 64-row half, 64-col quarter
    int srow = tid >> 2, sc8 = (tid & 3) * 8;
    int lr = l & 15, lg = l >> 4;
    int acol = lg * 8;

    f32x4 zz = {0.f, 0.f, 0.f, 0.f};
    f32x4 acc[4][4];
    #pragma unroll
    for (int i = 0; i < 4; ++i)
        #pragma unroll
        for (int j = 0; j < 4; ++j) acc[i][j] = zz;

    for (int k0 = 0; k0 < DD; k0 += 32) {
        __syncthreads();
        {   // stage 128x32 of x, f32 -> f16
            const float* src = x + (long)(m0 + srow) * DD + k0 + sc8;
            f32x4 a = *(const f32x4*)src;
            f32x4 b = *(const f32x4*)(src + 4);
            half8 h;
            h[0] = (_Float16)a[0]; h[1] = (_Float16)a[1];
            h[2] = (_Float16)a[2]; h[3] = (_Float16)a[3];
            h[4] = (_Float16)b[0]; h[5] = (_Float16)b[1];
            h[6] = (_Float16)b[2]; h[7] = (_Float16)b[3];
            *(half8*)&As[srow][sc8] = h;
        }
        __syncthreads();
        half8 af[4];
        #pragma unroll
        for (int rt = 0; rt < 4; ++rt)
            af[rt] = *(const half8*)&As[wr * 64 + rt * 16 + lr][acol];
        #pragma unroll
        for (int ct = 0; ct < 4; ++ct) {
            half8 bf = *(const half8*)(Wm + (long)(wc * 64 + ct * 16 + lr) * DD + k0 + acol);
            #pragma unroll
            for (int rt = 0; rt < 4; ++rt)
                acc[rt][ct] = __builtin_amdgcn_mfma_f32_16x16x32_f16(af[rt], bf, acc[rt][ct], 0, 0, 0);
        }
    }
    #pragma unroll
    for (int ct = 0; ct < 4; ++ct) {
        int col = wc * 64 + ct * 16 + lr;
        float bi = bias[col];
        #pragma unroll
        for (int rt = 0; rt < 4; ++rt)
            #pragma unroll
            for (int r = 0; r < 4; ++r) {
                int row = m0 + wr * 64 + rt * 16 + lg * 4 + r;
                Out[(long)row * DD + col] = (_Float16)(acc[rt][ct][r] + bi);
            }
    }
}

// ---- K2: flash-style scores: out[b,n] = sum_m softmax(QK^T/16)[n,m] * S[b,m]
// grid (32 q-tiles, 32 batches), 256 threads. Block = 64 q-rows; loop 64-row K tiles.
__global__ __launch_bounds__(256) void k_flash(
    const _Float16* __restrict__ Qh, const _Float16* __restrict__ Kh,
    const float* __restrict__ S, float* __restrict__ out) {
    __shared__ _Float16 Ks[64][264];  // 256 + 8 pad
    __shared__ float Ss[64];
    int b = blockIdx.y;
    int q0 = blockIdx.x * 64;
    const _Float16* Qb = Qh + (long)b * NN * DD;
    const _Float16* Kb = Kh + (long)b * NN * DD;
    int tid = threadIdx.x, w = tid >> 6, l = tid & 63;
    int lr = l & 15, lg = l >> 4;

    half8 qf[8];
    #pragma unroll
    for (int kk = 0; kk < 8; ++kk)
        qf[kk] = *(const half8*)(Qb + (long)(q0 + w * 16 + lr) * DD + kk * 32 + lg * 8);

    float M[4], Z[4], Y[4];
    #pragma unroll
    for (int r = 0; r < 4; ++r) { M[r] = -1e30f; Z[r] = 0.f; Y[r] = 0.f; }

    for (int m0 = 0; m0 < NN; m0 += 64) {
        __syncthreads();
        #pragma unroll
        for (int it = 0; it < 8; ++it) {
            int cid = it * 256 + tid;
            int row = cid >> 5, c8 = (cid & 31) * 8;
            *(half8*)&Ks[row][c8] = *(const half8*)(Kb + (long)(m0 + row) * DD + c8);
        }
        if (tid < 64) Ss[tid] = S[b * NN + m0 + tid];
        __syncthreads();

        f32x4 zz = {0.f, 0.f, 0.f, 0.f};
        f32x4 acc[4];
        #pragma unroll
        for (int ct = 0; ct < 4; ++ct) acc[ct] = zz;
        #pragma unroll
        for (int kk = 0; kk < 8; ++kk)
            #pragma unroll
            for (int ct = 0; ct < 4; ++ct) {
                half8 kf = *(const half8*)&Ks[ct * 16 + lr][kk * 32 + lg * 8];
                acc[ct] = __builtin_amdgcn_mfma_f32_16x16x32_f16(qf[kk], kf, acc[ct], 0, 0, 0);
            }

        float sv0 = Ss[lr], sv1 = Ss[16 + lr], sv2 = Ss[32 + lr], sv3 = Ss[48 + lr];
        #pragma unroll
        for (int rr = 0; rr < 4; ++rr) {
            float v0 = acc[0][rr] * SCALE, v1 = acc[1][rr] * SCALE;
            float v2 = acc[2][rr] * SCALE, v3 = acc[3][rr] * SCALE;
            float mx = fmaxf(fmaxf(v0, v1), fmaxf(v2, v3));
            #pragma unroll
            for (int d = 1; d < 16; d <<= 1) mx = fmaxf(mx, __shfl_xor(mx, d, 64));
            float nm = fmaxf(M[rr], mx);
            float corr = __expf(M[rr] - nm);
            float p0 = __expf(v0 - nm), p1 = __expf(v1 - nm);
            float p2 = __expf(v2 - nm), p3 = __expf(v3 - nm);
            float sp = p0 + p1 + p2 + p3;
            float sps = p0 * sv0 + p1 * sv1 + p2 * sv2 + p3 * sv3;
            #pragma unroll
            for (int d = 1; d < 16; d <<= 1) {
                sp += __shfl_xor(sp, d, 64);
                sps += __shfl_xor(sps, d, 64);
            }
            Z[rr] = Z[rr] * corr + sp;
            Y[rr] = Y[rr] * corr + sps;
            M[rr] = nm;
        }
    }
    if (lr == 0) {
        #pragma unroll
        for (int rr = 0; rr < 4; ++rr)
            out[b * NN + q0 + w * 16 + lg * 4 + rr] = Y[rr] / Z[rr];
    }
}

extern "C" void kernel_launch(void* const* d_in, const int* in_sizes, int n_in,
                              void* d_out, int out_size, void* d_ws, size_t ws_size,
                              hipStream_t stream) {
    const float* x  = (const float*)d_in[0];
    const float* Wq = (const float*)d_in[1];
    const float* bq = (const float*)d_in[2];
    const float* Wk = (const float*)d_in[3];
    const float* bk = (const float*)d_in[4];
    const float* Wv = (const float*)d_in[5];
    const float* bv = (const float*)d_in[6];
    const float* Ww = (const float*)d_in[7];
    const float* bw = (const float*)d_in[8];
    char* ws = (char*)d_ws;
    // workspace layout: Qh 32MB | Kh 32MB | Wt 256KB | S 256KB | wv 4KB  (~64.5MB)
    _Float16* Qh = (_Float16*)(ws);
    _Float16* Kh = (_Float16*)(ws + 33554432);
    _Float16* Wt = (_Float16*)(ws + 67108864);
    float* S     = (float*)(ws + 67108864 + 262144);
    float* wv    = (float*)(ws + 67108864 + 262144 + 262144);
    float* outp  = (float*)d_out;

    k_cvt_w<<<dim3(512), dim3(256), 0, stream>>>(Wq, Wk, Wt);
    k_wv<<<dim3(1), dim3(256), 0, stream>>>(Wv, bv, Ww, bw, wv);
    k_s<<<dim3(256), dim3(256), 0, stream>>>(x, wv, S);
    k_proj<<<dim3(512, 2), dim3(512), 0, stream>>>(x, Wt, bq, bk, Qh, Kh);
    k_flash<<<dim3(32, 32), dim3(256), 0, stream>>>(Qh, Kh, S, outp);
}

// Round 2
// 304.587 us; speedup vs baseline: 1.1657x; 1.1657x over previous
//
#include <hip/hip_runtime.h>
#include <hip/hip_fp16.h>

typedef _Float16 half8 __attribute__((ext_vector_type(8)));
typedef float f32x4 __attribute__((ext_vector_type(4)));

#define BB 32
#define NN 2048
#define DD 256
#define SCALE 0.0625f

__device__ __forceinline__ void gload_lds16(const void* g, void* l) {
    __builtin_amdgcn_global_load_lds(
        (const __attribute__((address_space(1))) void*)g,
        (__attribute__((address_space(3))) void*)l, 16, 0, 0);
}

// ---- P1: Wt[mat][c][k] = W[k][c], f16.  (mat 0 = Wq, 1 = Wk)
__global__ void k_cvt_w(const float* __restrict__ Wq, const float* __restrict__ Wk,
                        _Float16* __restrict__ Wt) {
    int idx = blockIdx.x * 256 + threadIdx.x;  // 131072 total
    int mat = idx >> 16;
    int c = (idx >> 8) & 255;
    int k = idx & 255;
    const float* W = mat ? Wk : Wq;
    Wt[idx] = (_Float16)W[k * 256 + c];
}

// ---- P2: wv[d] = sum_e Wv[d,e]*Ww[e]; wv[256] = bv.Ww + bw.  One wave per row.
__global__ void k_wv(const float* __restrict__ Wv, const float* __restrict__ bv,
                     const float* __restrict__ Ww, const float* __restrict__ bw,
                     float* __restrict__ wv) {
    int gw = (blockIdx.x * 256 + threadIdx.x) >> 6;
    int lane = threadIdx.x & 63;
    if (gw > 256) return;
    const float* row = (gw < 256) ? (Wv + gw * 256) : bv;
    f32x4 a = *((const f32x4*)row + lane);
    f32x4 wk = *((const f32x4*)Ww + lane);
    float p = a[0] * wk[0] + a[1] * wk[1] + a[2] * wk[2] + a[3] * wk[3];
    #pragma unroll
    for (int m = 1; m < 64; m <<= 1) p += __shfl_xor(p, m, 64);
    if (lane == 0) wv[gw] = (gw < 256) ? p : (p + bw[0]);
}

// ---- P3: S[r] = x[r,:].wv + wv[256]   (one wave per row-iteration)
__global__ void k_s(const float* __restrict__ x, const float* __restrict__ wv,
                    float* __restrict__ S) {
    int gtid = blockIdx.x * 256 + threadIdx.x;
    int wave = gtid >> 6;
    int lane = threadIdx.x & 63;
    f32x4 wvv = *((const f32x4*)wv + lane);
    float cst = wv[DD];
    for (int r = wave; r < BB * NN; r += 1024) {
        f32x4 xv = *((const f32x4*)(x + (long)r * DD) + lane);
        float p = xv[0] * wvv[0] + xv[1] * wvv[1] + xv[2] * wvv[2] + xv[3] * wvv[3];
        #pragma unroll
        for (int m = 1; m < 64; m <<= 1) p += __shfl_xor(p, m, 64);
        if (lane == 0) S[r] = p + cst;
    }
}

// ---- K1: Q and K projection GEMM, one x-staging for both mats.
// grid 512 row-tiles, 512 threads. Block: 128 rows x 256 cols x 2 mats.
__global__ __launch_bounds__(512, 2) void k_proj(
    const float* __restrict__ x, const _Float16* __restrict__ Wt,
    const float* __restrict__ bq, const float* __restrict__ bk,
    _Float16* __restrict__ Qh, _Float16* __restrict__ Kh) {
    __shared__ _Float16 As[128][40];  // 32 k-cols + 8 pad
    int m0 = blockIdx.x * 128;
    int tid = threadIdx.x, w = tid >> 6, l = tid & 63;
    int wr = w >> 2, wc = w & 3;
    int srow = tid >> 2, sc8 = (tid & 3) * 8;
    int lr = l & 15, lg = l >> 4;
    int acol = lg * 8;

    f32x4 zz = {0.f, 0.f, 0.f, 0.f};
    f32x4 acc[2][4][4];
    #pragma unroll
    for (int m = 0; m < 2; ++m)
        #pragma unroll
        for (int i = 0; i < 4; ++i)
            #pragma unroll
            for (int j = 0; j < 4; ++j) acc[m][i][j] = zz;

    for (int k0 = 0; k0 < DD; k0 += 32) {
        __syncthreads();
        {   // stage 128x32 of x, f32 -> f16
            const float* src = x + (long)(m0 + srow) * DD + k0 + sc8;
            f32x4 a = *(const f32x4*)src;
            f32x4 b = *(const f32x4*)(src + 4);
            half8 h;
            h[0] = (_Float16)a[0]; h[1] = (_Float16)a[1];
            h[2] = (_Float16)a[2]; h[3] = (_Float16)a[3];
            h[4] = (_Float16)b[0]; h[5] = (_Float16)b[1];
            h[6] = (_Float16)b[2]; h[7] = (_Float16)b[3];
            *(half8*)&As[srow][sc8] = h;
        }
        __syncthreads();
        half8 af[4];
        #pragma unroll
        for (int rt = 0; rt < 4; ++rt)
            af[rt] = *(const half8*)&As[wr * 64 + rt * 16 + lr][acol];
        #pragma unroll
        for (int mat = 0; mat < 2; ++mat)
            #pragma unroll
            for (int ct = 0; ct < 4; ++ct) {
                half8 bf = *(const half8*)(Wt + mat * 65536 +
                                           (long)(wc * 64 + ct * 16 + lr) * DD + k0 + acol);
                #pragma unroll
                for (int rt = 0; rt < 4; ++rt)
                    acc[mat][rt][ct] =
                        __builtin_amdgcn_mfma_f32_16x16x32_f16(af[rt], bf, acc[mat][rt][ct], 0, 0, 0);
            }
    }
    #pragma unroll
    for (int mat = 0; mat < 2; ++mat) {
        const float* bias = mat ? bk : bq;
        _Float16* Out = mat ? Kh : Qh;
        #pragma unroll
        for (int ct = 0; ct < 4; ++ct) {
            int col = wc * 64 + ct * 16 + lr;
            float bi = bias[col];
            #pragma unroll
            for (int rt = 0; rt < 4; ++rt)
                #pragma unroll
                for (int r = 0; r < 4; ++r) {
                    int row = m0 + wr * 64 + rt * 16 + lg * 4 + r;
                    Out[(long)row * DD + col] = (_Float16)(acc[mat][rt][ct][r] + bi);
                }
        }
    }
}

// ---- K2: out[b,n] = sum_m softmax(QK^T/16)[n,m] * S[b,m]
// Swapped-operand MFMA: lane holds 16 scores of ONE q-row -> in-lane softmax,
// no max subtraction (logits bounded ~16), lg-reduction deferred to end.
// K tile staged via global_load_lds w/ chunk^row&7 XOR swizzle (both sides).
__global__ __launch_bounds__(256) void k_flash(
    const _Float16* __restrict__ Qh, const _Float16* __restrict__ Kh,
    const float* __restrict__ S, float* __restrict__ out) {
    __shared__ _Float16 Ks[64][256];  // linear (gload_lds dest), XOR-swizzled content
    int b = blockIdx.y;
    int q0 = blockIdx.x * 64;
    const _Float16* Qb = Qh + (long)b * NN * DD;
    const _Float16* Kb = Kh + (long)b * NN * DD;
    const float* Sb = S + b * NN;
    int tid = threadIdx.x, w = tid >> 6, l = tid & 63;
    int lr = l & 15, lg = l >> 4;
    int l5 = l >> 5, c32 = l & 31;
    int rx = lr & 7;

    half8 qf[8];
    #pragma unroll
    for (int kk = 0; kk < 8; ++kk)
        qf[kk] = *(const half8*)(Qb + (long)(q0 + w * 16 + lr) * DD + kk * 32 + lg * 8);

    float z = 0.f, y = 0.f;

    for (int m0 = 0; m0 < NN; m0 += 64) {
        __syncthreads();  // all waves done reading Ks of previous tile
        #pragma unroll
        for (int i = 0; i < 8; ++i) {
            int rt = (w * 8 + i) * 2 + l5;  // row in tile this lane sources
            const _Float16* src = Kb + (long)(m0 + rt) * DD + ((c32 ^ (rt & 7)) * 8);
            gload_lds16(src, &Ks[(w * 8 + i) * 2][0]);
        }
        asm volatile("s_waitcnt vmcnt(0)");
        __syncthreads();

        f32x4 zz = {0.f, 0.f, 0.f, 0.f};
        f32x4 acc[4] = {zz, zz, zz, zz};
        #pragma unroll
        for (int kk = 0; kk < 8; ++kk) {
            int pc = ((kk * 4 + lg) ^ rx) * 8;
            #pragma unroll
            for (int ct = 0; ct < 4; ++ct) {
                half8 kf = *(const half8*)&Ks[ct * 16 + lr][pc];
                acc[ct] = __builtin_amdgcn_mfma_f32_16x16x32_f16(kf, qf[kk], acc[ct], 0, 0, 0);
            }
        }
        #pragma unroll
        for (int ct = 0; ct < 4; ++ct) {
            f32x4 sv = *(const f32x4*)(Sb + m0 + ct * 16 + lg * 4);
            #pragma unroll
            for (int r = 0; r < 4; ++r) {
                float e = __expf(acc[ct][r] * SCALE);
                z += e;
                y += e * sv[r];
            }
        }
    }
    y += __shfl_xor(y, 16, 64);
    y += __shfl_xor(y, 32, 64);
    z += __shfl_xor(z, 16, 64);
    z += __shfl_xor(z, 32, 64);
    if (l < 16) out[b * NN + q0 + w * 16 + lr] = y / z;
}

extern "C" void kernel_launch(void* const* d_in, const int* in_sizes, int n_in,
                              void* d_out, int out_size, void* d_ws, size_t ws_size,
                              hipStream_t stream) {
    const float* x  = (const float*)d_in[0];
    const float* Wq = (const float*)d_in[1];
    const float* bq = (const float*)d_in[2];
    const float* Wk = (const float*)d_in[3];
    const float* bk = (const float*)d_in[4];
    const float* Wv = (const float*)d_in[5];
    const float* bv = (const float*)d_in[6];
    const float* Ww = (const float*)d_in[7];
    const float* bw = (const float*)d_in[8];
    char* ws = (char*)d_ws;
    // workspace layout: Qh 32MB | Kh 32MB | Wt 256KB | S 256KB | wv 4KB
    _Float16* Qh = (_Float16*)(ws);
    _Float16* Kh = (_Float16*)(ws + 33554432);
    _Float16* Wt = (_Float16*)(ws + 67108864);
    float* S     = (float*)(ws + 67108864 + 262144);
    float* wv    = (float*)(ws + 67108864 + 262144 + 262144);
    float* outp  = (float*)d_out;

    k_cvt_w<<<dim3(512), dim3(256), 0, stream>>>(Wq, Wk, Wt);
    k_wv<<<dim3(65), dim3(256), 0, stream>>>(Wv, bv, Ww, bw, wv);
    k_s<<<dim3(256), dim3(256), 0, stream>>>(x, wv, S);
    k_proj<<<dim3(512), dim3(512), 0, stream>>>(x, Wt, bq, bk, Qh, Kh);
    k_flash<<<dim3(32, 32), dim3(256), 0, stream>>>(Qh, Kh, S, outp);
}

// Round 3
// 273.820 us; speedup vs baseline: 1.2967x; 1.1124x over previous
//
#include <hip/hip_runtime.h>
#include <hip/hip_fp16.h>

typedef _Float16 half8 __attribute__((ext_vector_type(8)));
typedef float f32x4 __attribute__((ext_vector_type(4)));

#define BB 32
#define NN 2048
#define DD 256
#define SCALE 0.0625f

__device__ __forceinline__ void gload_lds16(const void* g, void* l) {
    __builtin_amdgcn_global_load_lds(
        (const __attribute__((address_space(1))) void*)g,
        (__attribute__((address_space(3))) void*)l, 16, 0, 0);
}

// ---- P1: blocks 0..511: Wt[mat][c][k] = W[k][c] f16 (coalesced reads).
//          blocks 512..576: wv[d] = Wv[d,:].Ww ; wv[256] = bv.Ww + bw
__global__ void k_pre(const float* __restrict__ Wq, const float* __restrict__ Wk,
                      const float* __restrict__ Wv, const float* __restrict__ bv,
                      const float* __restrict__ Ww, const float* __restrict__ bw,
                      _Float16* __restrict__ Wt, float* __restrict__ wv) {
    if (blockIdx.x < 512) {
        int idx = blockIdx.x * 256 + threadIdx.x;  // 131072
        int mat = idx >> 16;
        int r = (idx >> 8) & 255;
        int c = idx & 255;
        const float* W = mat ? Wk : Wq;
        Wt[mat * 65536 + c * 256 + r] = (_Float16)W[r * 256 + c];
    } else {
        int gw = ((blockIdx.x - 512) * 256 + (int)threadIdx.x) >> 6;
        int lane = threadIdx.x & 63;
        if (gw > 256) return;
        const float* row = (gw < 256) ? (Wv + gw * 256) : bv;
        f32x4 a = *((const f32x4*)row + lane);
        f32x4 wk = *((const f32x4*)Ww + lane);
        float p = a[0] * wk[0] + a[1] * wk[1] + a[2] * wk[2] + a[3] * wk[3];
        #pragma unroll
        for (int m = 1; m < 64; m <<= 1) p += __shfl_xor(p, m, 64);
        if (lane == 0) wv[gw] = (gw < 256) ? p : (p + bw[0]);
    }
}

// ---- K1: Q and K projection GEMM + fused S = x.wv + cst.
// grid 512 row-tiles, 512 threads. Block: 128 rows x 256 cols x 2 mats.
__global__ __launch_bounds__(512, 2) void k_proj(
    const float* __restrict__ x, const _Float16* __restrict__ Wt,
    const float* __restrict__ bq, const float* __restrict__ bk,
    const float* __restrict__ wv,
    _Float16* __restrict__ Qh, _Float16* __restrict__ Kh, float* __restrict__ S) {
    __shared__ _Float16 As[128][40];  // 32 k-cols + 8 pad
    int m0 = blockIdx.x * 128;
    int tid = threadIdx.x, w = tid >> 6, l = tid & 63;
    int wr = w >> 2, wc = w & 3;
    int srow = tid >> 2, sc8 = (tid & 3) * 8;
    int lr = l & 15, lg = l >> 4;
    int acol = lg * 8;
    float sacc = 0.f;

    f32x4 zz = {0.f, 0.f, 0.f, 0.f};
    f32x4 acc[2][4][4];
    #pragma unroll
    for (int m = 0; m < 2; ++m)
        #pragma unroll
        for (int i = 0; i < 4; ++i)
            #pragma unroll
            for (int j = 0; j < 4; ++j) acc[m][i][j] = zz;

    for (int k0 = 0; k0 < DD; k0 += 32) {
        __syncthreads();
        {   // stage 128x32 of x f32->f16; fold partial S-dot in f32
            const float* src = x + (long)(m0 + srow) * DD + k0 + sc8;
            f32x4 a = *(const f32x4*)src;
            f32x4 b = *(const f32x4*)(src + 4);
            f32x4 wa = *(const f32x4*)(wv + k0 + sc8);
            f32x4 wb = *(const f32x4*)(wv + k0 + sc8 + 4);
            sacc += a[0] * wa[0] + a[1] * wa[1] + a[2] * wa[2] + a[3] * wa[3]
                  + b[0] * wb[0] + b[1] * wb[1] + b[2] * wb[2] + b[3] * wb[3];
            half8 h;
            h[0] = (_Float16)a[0]; h[1] = (_Float16)a[1];
            h[2] = (_Float16)a[2]; h[3] = (_Float16)a[3];
            h[4] = (_Float16)b[0]; h[5] = (_Float16)b[1];
            h[6] = (_Float16)b[2]; h[7] = (_Float16)b[3];
            *(half8*)&As[srow][sc8] = h;
        }
        __syncthreads();
        half8 af[4];
        #pragma unroll
        for (int rt = 0; rt < 4; ++rt)
            af[rt] = *(const half8*)&As[wr * 64 + rt * 16 + lr][acol];
        #pragma unroll
        for (int mat = 0; mat < 2; ++mat)
            #pragma unroll
            for (int ct = 0; ct < 4; ++ct) {
                half8 bf = *(const half8*)(Wt + mat * 65536 +
                                           (long)(wc * 64 + ct * 16 + lr) * DD + k0 + acol);
                #pragma unroll
                for (int rt = 0; rt < 4; ++rt)
                    acc[mat][rt][ct] =
                        __builtin_amdgcn_mfma_f32_16x16x32_f16(af[rt], bf, acc[mat][rt][ct], 0, 0, 0);
            }
    }
    // S: reduce 4 quarter-sums (lanes differing in bits 0-1, same wave)
    sacc += __shfl_xor(sacc, 1, 64);
    sacc += __shfl_xor(sacc, 2, 64);
    if ((tid & 3) == 0) S[m0 + srow] = sacc + wv[DD];

    #pragma unroll
    for (int mat = 0; mat < 2; ++mat) {
        const float* bias = mat ? bk : bq;
        _Float16* Out = mat ? Kh : Qh;
        #pragma unroll
        for (int ct = 0; ct < 4; ++ct) {
            int col = wc * 64 + ct * 16 + lr;
            float bi = bias[col];
            #pragma unroll
            for (int rt = 0; rt < 4; ++rt)
                #pragma unroll
                for (int r = 0; r < 4; ++r) {
                    int row = m0 + wr * 64 + rt * 16 + lg * 4 + r;
                    Out[(long)row * DD + col] = (_Float16)(acc[mat][rt][ct][r] + bi);
                }
        }
    }
}

// ---- K2: out[b,n] = sum_m softmax(QK^T/16)[n,m] * S[b,m]
// 256 q-rows/block (64/wave), grid 256 = 1 block/CU, batch-clustered per XCD.
// Double-buffered K tile via global_load_lds, chunk^row&7 XOR swizzle.
// Swapped-operand MFMA -> in-lane softmax, no max subtraction.
__global__ __launch_bounds__(256, 2) void k_flash(
    const _Float16* __restrict__ Qh, const _Float16* __restrict__ Kh,
    const float* __restrict__ S, float* __restrict__ out) {
    __shared__ _Float16 Ks[2][64][256];  // 64 KB double buffer
    int u = blockIdx.x;
    int b = (u & 7) | (((u >> 3) & 3) << 3);  // u%8 -> XCD; batch pinned to XCD b%8
    int q0 = (u >> 5) * 256;
    const _Float16* Qb = Qh + (long)b * NN * DD;
    const _Float16* Kb = Kh + (long)b * NN * DD;
    const float* Sb = S + b * NN;
    int tid = threadIdx.x, w = tid >> 6, l = tid & 63;
    int lr = l & 15, lg = l >> 4;
    int l5 = l >> 5, c32 = l & 31;
    int rx = lr & 7;

    half8 qf[4][8];
    #pragma unroll
    for (int qa = 0; qa < 4; ++qa)
        #pragma unroll
        for (int kk = 0; kk < 8; ++kk)
            qf[qa][kk] = *(const half8*)(Qb + (long)(q0 + w * 64 + qa * 16 + lr) * DD + kk * 32 + lg * 8);

    float z[4] = {0.f, 0.f, 0.f, 0.f}, y[4] = {0.f, 0.f, 0.f, 0.f};

    // prologue: stage tile 0 into buf 0
    #pragma unroll
    for (int i = 0; i < 8; ++i) {
        int rt = (w * 8 + i) * 2 + l5;
        gload_lds16(Kb + (long)rt * DD + ((c32 ^ (rt & 7)) * 8), &Ks[0][(w * 8 + i) * 2][0]);
    }
    asm volatile("s_waitcnt vmcnt(0)" ::: "memory");
    __syncthreads();

    int cur = 0;
    for (int t = 0; t < 32; ++t) {
        int m0 = t * 64;
        if (t < 31) {  // prefetch next tile into buf^1
            #pragma unroll
            for (int i = 0; i < 8; ++i) {
                int rt = (w * 8 + i) * 2 + l5;
                gload_lds16(Kb + (long)(m0 + 64 + rt) * DD + ((c32 ^ (rt & 7)) * 8),
                            &Ks[cur ^ 1][(w * 8 + i) * 2][0]);
            }
        }
        f32x4 zz = {0.f, 0.f, 0.f, 0.f};
        f32x4 acc[4][4];
        #pragma unroll
        for (int qa = 0; qa < 4; ++qa)
            #pragma unroll
            for (int ct = 0; ct < 4; ++ct) acc[qa][ct] = zz;

        #pragma unroll
        for (int kk = 0; kk < 8; ++kk) {
            int pc = ((kk * 4 + lg) ^ rx) * 8;
            half8 kf[4];
            #pragma unroll
            for (int ct = 0; ct < 4; ++ct)
                kf[ct] = *(const half8*)&Ks[cur][ct * 16 + lr][pc];
            #pragma unroll
            for (int ct = 0; ct < 4; ++ct)
                #pragma unroll
                for (int qa = 0; qa < 4; ++qa)
                    acc[qa][ct] = __builtin_amdgcn_mfma_f32_16x16x32_f16(kf[ct], qf[qa][kk], acc[qa][ct], 0, 0, 0);
        }
        #pragma unroll
        for (int ct = 0; ct < 4; ++ct) {
            f32x4 sv = *(const f32x4*)(Sb + m0 + ct * 16 + lg * 4);
            #pragma unroll
            for (int qa = 0; qa < 4; ++qa)
                #pragma unroll
                for (int r = 0; r < 4; ++r) {
                    float e = __expf(acc[qa][ct][r] * SCALE);
                    z[qa] += e;
                    y[qa] = fmaf(e, sv[r], y[qa]);
                }
        }
        asm volatile("s_waitcnt vmcnt(0)" ::: "memory");
        __syncthreads();
        cur ^= 1;
    }
    #pragma unroll
    for (int qa = 0; qa < 4; ++qa) {
        y[qa] += __shfl_xor(y[qa], 16, 64);
        y[qa] += __shfl_xor(y[qa], 32, 64);
        z[qa] += __shfl_xor(z[qa], 16, 64);
        z[qa] += __shfl_xor(z[qa], 32, 64);
    }
    if (l < 16)
        #pragma unroll
        for (int qa = 0; qa < 4; ++qa)
            out[b * NN + q0 + w * 64 + qa * 16 + lr] = y[qa] / z[qa];
}

extern "C" void kernel_launch(void* const* d_in, const int* in_sizes, int n_in,
                              void* d_out, int out_size, void* d_ws, size_t ws_size,
                              hipStream_t stream) {
    const float* x  = (const float*)d_in[0];
    const float* Wq = (const float*)d_in[1];
    const float* bq = (const float*)d_in[2];
    const float* Wk = (const float*)d_in[3];
    const float* bk = (const float*)d_in[4];
    const float* Wv = (const float*)d_in[5];
    const float* bv = (const float*)d_in[6];
    const float* Ww = (const float*)d_in[7];
    const float* bw = (const float*)d_in[8];
    char* ws = (char*)d_ws;
    // workspace layout: Qh 32MB | Kh 32MB | Wt 256KB | S 256KB | wv 4KB
    _Float16* Qh = (_Float16*)(ws);
    _Float16* Kh = (_Float16*)(ws + 33554432);
    _Float16* Wt = (_Float16*)(ws + 67108864);
    float* S     = (float*)(ws + 67108864 + 262144);
    float* wv    = (float*)(ws + 67108864 + 262144 + 262144);
    float* outp  = (float*)d_out;

    k_pre<<<dim3(577), dim3(256), 0, stream>>>(Wq, Wk, Wv, bv, Ww, bw, Wt, wv);
    k_proj<<<dim3(512), dim3(512), 0, stream>>>(x, Wt, bq, bk, wv, Qh, Kh, S);
    k_flash<<<dim3(256), dim3(256), 0, stream>>>(Qh, Kh, S, outp);
}

// Round 4
// 218.465 us; speedup vs baseline: 1.6253x; 1.2534x over previous
//
#include <hip/hip_runtime.h>
#include <hip/hip_fp16.h>

typedef _Float16 half8 __attribute__((ext_vector_type(8)));
typedef float f32x4 __attribute__((ext_vector_type(4)));

#define BB 32
#define NN 2048
#define DD 256
#define SCALE 0.0625f

__device__ __forceinline__ void gload_lds16(const void* g, void* l) {
    __builtin_amdgcn_global_load_lds(
        (const __attribute__((address_space(1))) void*)g,
        (__attribute__((address_space(3))) void*)l, 16, 0, 0);
}

// ---- P1: blocks 0..511: Wt[mat][c][k] = W[k][c] f16 (coalesced reads).
//          blocks 512..576: wv[d] = Wv[d,:].Ww ; wv[256] = bv.Ww + bw
__global__ void k_pre(const float* __restrict__ Wq, const float* __restrict__ Wk,
                      const float* __restrict__ Wv, const float* __restrict__ bv,
                      const float* __restrict__ Ww, const float* __restrict__ bw,
                      _Float16* __restrict__ Wt, float* __restrict__ wv) {
    if (blockIdx.x < 512) {
        int idx = blockIdx.x * 256 + threadIdx.x;  // 131072
        int mat = idx >> 16;
        int r = (idx >> 8) & 255;
        int c = idx & 255;
        const float* W = mat ? Wk : Wq;
        Wt[mat * 65536 + c * 256 + r] = (_Float16)W[r * 256 + c];
    } else {
        int gw = ((blockIdx.x - 512) * 256 + (int)threadIdx.x) >> 6;
        int lane = threadIdx.x & 63;
        if (gw > 256) return;
        const float* row = (gw < 256) ? (Wv + gw * 256) : bv;
        f32x4 a = *((const f32x4*)row + lane);
        f32x4 wk = *((const f32x4*)Ww + lane);
        float p = a[0] * wk[0] + a[1] * wk[1] + a[2] * wk[2] + a[3] * wk[3];
        #pragma unroll
        for (int m = 1; m < 64; m <<= 1) p += __shfl_xor(p, m, 64);
        if (lane == 0) wv[gw] = (gw < 256) ? p : (p + bw[0]);
    }
}

// ---- K1: Q and K projection GEMM + fused S = x.wv + cst.
// grid 512 row-tiles, 512 threads. Block: 128 rows x 256 cols x 2 mats.
__global__ __launch_bounds__(512, 2) void k_proj(
    const float* __restrict__ x, const _Float16* __restrict__ Wt,
    const float* __restrict__ bq, const float* __restrict__ bk,
    const float* __restrict__ wv,
    _Float16* __restrict__ Qh, _Float16* __restrict__ Kh, float* __restrict__ S) {
    __shared__ _Float16 As[128][40];  // 32 k-cols + 8 pad
    int m0 = blockIdx.x * 128;
    int tid = threadIdx.x, w = tid >> 6, l = tid & 63;
    int wr = w >> 2, wc = w & 3;
    int srow = tid >> 2, sc8 = (tid & 3) * 8;
    int lr = l & 15, lg = l >> 4;
    int acol = lg * 8;
    float sacc = 0.f;

    f32x4 zz = {0.f, 0.f, 0.f, 0.f};
    f32x4 acc[2][4][4];
    #pragma unroll
    for (int m = 0; m < 2; ++m)
        #pragma unroll
        for (int i = 0; i < 4; ++i)
            #pragma unroll
            for (int j = 0; j < 4; ++j) acc[m][i][j] = zz;

    for (int k0 = 0; k0 < DD; k0 += 32) {
        __syncthreads();
        {   // stage 128x32 of x f32->f16; fold partial S-dot in f32
            const float* src = x + (long)(m0 + srow) * DD + k0 + sc8;
            f32x4 a = *(const f32x4*)src;
            f32x4 b = *(const f32x4*)(src + 4);
            f32x4 wa = *(const f32x4*)(wv + k0 + sc8);
            f32x4 wb = *(const f32x4*)(wv + k0 + sc8 + 4);
            sacc += a[0] * wa[0] + a[1] * wa[1] + a[2] * wa[2] + a[3] * wa[3]
                  + b[0] * wb[0] + b[1] * wb[1] + b[2] * wb[2] + b[3] * wb[3];
            half8 h;
            h[0] = (_Float16)a[0]; h[1] = (_Float16)a[1];
            h[2] = (_Float16)a[2]; h[3] = (_Float16)a[3];
            h[4] = (_Float16)b[0]; h[5] = (_Float16)b[1];
            h[6] = (_Float16)b[2]; h[7] = (_Float16)b[3];
            *(half8*)&As[srow][sc8] = h;
        }
        __syncthreads();
        half8 af[4];
        #pragma unroll
        for (int rt = 0; rt < 4; ++rt)
            af[rt] = *(const half8*)&As[wr * 64 + rt * 16 + lr][acol];
        #pragma unroll
        for (int mat = 0; mat < 2; ++mat)
            #pragma unroll
            for (int ct = 0; ct < 4; ++ct) {
                half8 bf = *(const half8*)(Wt + mat * 65536 +
                                           (long)(wc * 64 + ct * 16 + lr) * DD + k0 + acol);
                #pragma unroll
                for (int rt = 0; rt < 4; ++rt)
                    acc[mat][rt][ct] =
                        __builtin_amdgcn_mfma_f32_16x16x32_f16(af[rt], bf, acc[mat][rt][ct], 0, 0, 0);
            }
    }
    // S: reduce 4 quarter-sums (lanes differing in bits 0-1, same wave)
    sacc += __shfl_xor(sacc, 1, 64);
    sacc += __shfl_xor(sacc, 2, 64);
    if ((tid & 3) == 0) S[m0 + srow] = sacc + wv[DD];

    #pragma unroll
    for (int mat = 0; mat < 2; ++mat) {
        const float* bias = mat ? bk : bq;
        _Float16* Out = mat ? Kh : Qh;
        #pragma unroll
        for (int ct = 0; ct < 4; ++ct) {
            int col = wc * 64 + ct * 16 + lr;
            float bi = bias[col];
            #pragma unroll
            for (int rt = 0; rt < 4; ++rt)
                #pragma unroll
                for (int r = 0; r < 4; ++r) {
                    int row = m0 + wr * 64 + rt * 16 + lg * 4 + r;
                    Out[(long)row * DD + col] = (_Float16)(acc[mat][rt][ct][r] + bi);
                }
        }
    }
}

// ---- K2: out[b,n] = sum_m softmax(QK^T/16)[n,m] * S[b,m]
// 512 threads = 8 waves (2/SIMD for latency hiding), 32 q-rows/wave,
// 256 q-rows/block, grid 256 (1 block/CU), batch-clustered per XCD.
// Double-buffered 64-row K tile via global_load_lds, chunk^row&7 XOR swizzle.
// Swapped-operand MFMA -> in-lane softmax, no max subtraction.
__global__ __launch_bounds__(512, 2) void k_flash(
    const _Float16* __restrict__ Qh, const _Float16* __restrict__ Kh,
    const float* __restrict__ S, float* __restrict__ out) {
    __shared__ _Float16 Ks[2][64][256];  // 64 KB double buffer
    int u = blockIdx.x;
    int b = (u & 7) | (((u >> 3) & 3) << 3);  // u%8 -> XCD; batch pinned to XCD b%8
    int q0 = (u >> 5) * 256;
    const _Float16* Qb = Qh + (long)b * NN * DD;
    const _Float16* Kb = Kh + (long)b * NN * DD;
    const float* Sb = S + b * NN;
    int tid = threadIdx.x, w = tid >> 6, l = tid & 63;
    int lr = l & 15, lg = l >> 4;
    int l5 = l >> 5, c32 = l & 31;
    int rx = lr & 7;

    half8 qf[2][8];
    #pragma unroll
    for (int qa = 0; qa < 2; ++qa)
        #pragma unroll
        for (int kk = 0; kk < 8; ++kk)
            qf[qa][kk] = *(const half8*)(Qb + (long)(q0 + w * 32 + qa * 16 + lr) * DD + kk * 32 + lg * 8);

    float z[2] = {0.f, 0.f}, y[2] = {0.f, 0.f};

    // prologue: stage tile 0 into buf 0 (wave w stages rows w*8..w*8+7)
    #pragma unroll
    for (int i = 0; i < 4; ++i) {
        int rt = w * 8 + i * 2 + l5;
        gload_lds16(Kb + (long)rt * DD + ((c32 ^ (rt & 7)) * 8), &Ks[0][w * 8 + i * 2][0]);
    }
    asm volatile("s_waitcnt vmcnt(0)" ::: "memory");
    __syncthreads();

    int cur = 0;
    for (int t = 0; t < 32; ++t) {
        int m0 = t * 64;
        if (t < 31) {  // prefetch next tile into buf^1
            #pragma unroll
            for (int i = 0; i < 4; ++i) {
                int rt = w * 8 + i * 2 + l5;
                gload_lds16(Kb + (long)(m0 + 64 + rt) * DD + ((c32 ^ (rt & 7)) * 8),
                            &Ks[cur ^ 1][w * 8 + i * 2][0]);
            }
        }
        // issue S loads early; consumed after MFMA section (latency hidden)
        f32x4 sv[4];
        #pragma unroll
        for (int ct = 0; ct < 4; ++ct)
            sv[ct] = *(const f32x4*)(Sb + m0 + ct * 16 + lg * 4);

        f32x4 zz = {0.f, 0.f, 0.f, 0.f};
        f32x4 acc[2][4];
        #pragma unroll
        for (int qa = 0; qa < 2; ++qa)
            #pragma unroll
            for (int ct = 0; ct < 4; ++ct) acc[qa][ct] = zz;

        #pragma unroll
        for (int kk = 0; kk < 8; ++kk) {
            int pc = ((kk * 4 + lg) ^ rx) * 8;
            half8 kf[4];
            #pragma unroll
            for (int ct = 0; ct < 4; ++ct)
                kf[ct] = *(const half8*)&Ks[cur][ct * 16 + lr][pc];
            #pragma unroll
            for (int ct = 0; ct < 4; ++ct)
                #pragma unroll
                for (int qa = 0; qa < 2; ++qa)
                    acc[qa][ct] = __builtin_amdgcn_mfma_f32_16x16x32_f16(kf[ct], qf[qa][kk], acc[qa][ct], 0, 0, 0);
        }
        #pragma unroll
        for (int ct = 0; ct < 4; ++ct)
            #pragma unroll
            for (int qa = 0; qa < 2; ++qa)
                #pragma unroll
                for (int r = 0; r < 4; ++r) {
                    float e = __expf(acc[qa][ct][r] * SCALE);
                    z[qa] += e;
                    y[qa] = fmaf(e, sv[ct][r], y[qa]);
                }
        asm volatile("s_waitcnt vmcnt(0)" ::: "memory");
        __syncthreads();
        cur ^= 1;
    }
    #pragma unroll
    for (int qa = 0; qa < 2; ++qa) {
        y[qa] += __shfl_xor(y[qa], 16, 64);
        y[qa] += __shfl_xor(y[qa], 32, 64);
        z[qa] += __shfl_xor(z[qa], 16, 64);
        z[qa] += __shfl_xor(z[qa], 32, 64);
    }
    if (l < 16)
        #pragma unroll
        for (int qa = 0; qa < 2; ++qa)
            out[b * NN + q0 + w * 32 + qa * 16 + lr] = y[qa] / z[qa];
}

extern "C" void kernel_launch(void* const* d_in, const int* in_sizes, int n_in,
                              void* d_out, int out_size, void* d_ws, size_t ws_size,
                              hipStream_t stream) {
    const float* x  = (const float*)d_in[0];
    const float* Wq = (const float*)d_in[1];
    const float* bq = (const float*)d_in[2];
    const float* Wk = (const float*)d_in[3];
    const float* bk = (const float*)d_in[4];
    const float* Wv = (const float*)d_in[5];
    const float* bv = (const float*)d_in[6];
    const float* Ww = (const float*)d_in[7];
    const float* bw = (const float*)d_in[8];
    char* ws = (char*)d_ws;
    // workspace layout: Qh 32MB | Kh 32MB | Wt 256KB | S 256KB | wv 4KB
    _Float16* Qh = (_Float16*)(ws);
    _Float16* Kh = (_Float16*)(ws + 33554432);
    _Float16* Wt = (_Float16*)(ws + 67108864);
    float* S     = (float*)(ws + 67108864 + 262144);
    float* wv    = (float*)(ws + 67108864 + 262144 + 262144);
    float* outp  = (float*)d_out;

    k_pre<<<dim3(577), dim3(256), 0, stream>>>(Wq, Wk, Wv, bv, Ww, bw, Wt, wv);
    k_proj<<<dim3(512), dim3(512), 0, stream>>>(x, Wt, bq, bk, wv, Qh, Kh, S);
    k_flash<<<dim3(256), dim3(512), 0, stream>>>(Qh, Kh, S, outp);
}